// Round 16
// baseline (210.654 us; speedup 1.0000x reference)
//
#include <hip/hip_runtime.h>
#include <stdint.h>

typedef signed char i8;
typedef unsigned char u8;
typedef __attribute__((ext_vector_type(4))) int i32x4;
typedef __attribute__((ext_vector_type(16))) int i32x16;

__device__ __forceinline__ void gload_lds16(const void* g, void* l) {
  __builtin_amdgcn_global_load_lds(
      (__attribute__((address_space(1))) void*)const_cast<void*>(g),
      (__attribute__((address_space(3))) void*)l, 16, 0, 0);
}

// ---------- fused prep: one grid quantizes both x (rows) and W' (rows) ----------
__global__ __launch_bounds__(256) void k_quant(const float* __restrict__ x,
                                               const float* __restrict__ W,
                                               const float* __restrict__ Am,
                                               const float* __restrict__ Bm,
                                               i8* __restrict__ xq,
                                               i8* __restrict__ wq,
                                               float* __restrict__ sx,
                                               float* __restrict__ sw, int M) {
  const int bid = blockIdx.x, t = threadIdx.x;
  const bool isx = bid < M;
  const int row = isx ? bid : bid - M;
  float4 v[4];
  float m = 0.f;
  if (isx) {
    const float4* src = (const float4*)(x + (size_t)row * 4096);
#pragma unroll
    for (int j = 0; j < 4; ++j) {
      v[j] = src[j * 256 + t];
      m = fmaxf(m, fmaxf(fmaxf(fabsf(v[j].x), fabsf(v[j].y)),
                         fmaxf(fabsf(v[j].z), fabsf(v[j].w))));
    }
  } else {
    const float4 b4 = *(const float4*)(Bm + (row << 2));
#pragma unroll
    for (int j = 0; j < 4; ++j) {
      const int i = (j * 256 + t) * 4;
      float4 w  = *(const float4*)(W + ((size_t)row << 12) + i);
      float4 a0 = *(const float4*)(Am + i);
      float4 a1 = *(const float4*)(Am + 4096 + i);
      float4 a2 = *(const float4*)(Am + 8192 + i);
      float4 a3 = *(const float4*)(Am + 12288 + i);
      w.x += 4.f * (b4.x * a0.x + b4.y * a1.x + b4.z * a2.x + b4.w * a3.x);
      w.y += 4.f * (b4.x * a0.y + b4.y * a1.y + b4.z * a2.y + b4.w * a3.y);
      w.z += 4.f * (b4.x * a0.z + b4.y * a1.z + b4.z * a2.z + b4.w * a3.z);
      w.w += 4.f * (b4.x * a0.w + b4.y * a1.w + b4.z * a2.w + b4.w * a3.w);
      v[j] = w;
      m = fmaxf(m, fmaxf(fmaxf(fabsf(w.x), fabsf(w.y)), fmaxf(fabsf(w.z), fabsf(w.w))));
    }
  }
#pragma unroll
  for (int off = 32; off; off >>= 1) m = fmaxf(m, __shfl_xor(m, off));
  __shared__ float wmax[4];
  if ((t & 63) == 0) wmax[t >> 6] = m;
  __syncthreads();
  m = fmaxf(fmaxf(wmax[0], wmax[1]), fmaxf(wmax[2], wmax[3]));
  const float inv = m > 0.f ? 127.f / m : 0.f;
  if (t == 0) { if (isx) sx[row] = m / 127.f; else sw[row] = m / 127.f; }
  i8* out = isx ? xq : wq;
#pragma unroll
  for (int j = 0; j < 4; ++j) {
    int q0 = (int)rintf(fmaxf(fminf(v[j].x * inv, 127.f), -127.f));
    int q1 = (int)rintf(fmaxf(fminf(v[j].y * inv, 127.f), -127.f));
    int q2 = (int)rintf(fmaxf(fminf(v[j].z * inv, 127.f), -127.f));
    int q3 = (int)rintf(fmaxf(fminf(v[j].w * inv, 127.f), -127.f));
    uint32_t p = (q0 & 255) | ((q1 & 255) << 8) | ((q2 & 255) << 16) | ((q3 & 255) << 24);
    *(uint32_t*)(out + (size_t)row * 4096 + (j * 256 + t) * 4) = p;
  }
}

// ===== i8 GEMM — R9 skeleton + mfma_i32_32x32x32_i8 (half the MFMA count) =====
// Staging/swizzle/phases/waits byte-identical to R9.  Fragment layer:
//   A-frag: row = lane&31, k = (lane>>5)*16 + s*32   (16 i8 = 1 b128)
//   B-frag: col = lane&31, same k                      (B^T rows)
//   C/D   : col = lane&31, row = (reg&3) + 8*(reg>>2) + 4*(lane>>5)  [m74/m101]
// Read swizzle: phys chunk = (s*2 + h) ^ (lane&7) with h = lane>>5 — under the
// R9 write swizzle (phys = c ^ (row&7)) each 16B bank-group gets exactly 8
// lanes with distinct addresses (bandwidth-uniform, conflict-free).
__global__ __launch_bounds__(512, 2) void k_gq8(const u8* __restrict__ Ag,
                                                const u8* __restrict__ Bg,
                                                const float* __restrict__ sx,
                                                const float* __restrict__ sw,
                                                float* __restrict__ C,
                                                int M, int N, int K) {
  __shared__ __attribute__((aligned(16))) u8 As[2 * 32768];
  __shared__ __attribute__((aligned(16))) u8 Bs[2 * 32768];
  const int tid  = threadIdx.x;
  const int wave = tid >> 6, lane = tid & 63;
  const int wr = wave >> 2, wc = wave & 3;
  const int m0 = blockIdx.y * 256, n0 = blockIdx.x * 256;
  const int NT = K >> 7;                           // 128-byte K-tiles

  // staging (R9 verbatim): unit = 64 rows x 128 B; phys chunk = c ^ (row&7)
  const int srow = tid >> 3;                       // 0..63
  const int csrc = (tid & 7) ^ (srow & 7);
  const u8* pA = Ag + (size_t)(m0 + srow) * K + csrc * 16;
  const u8* pB = Bg + (size_t)(n0 + srow) * K + csrc * 16;
  const size_t KH = (size_t)128 * K;
  const size_t KU = (size_t)64 * K;
  const int wb = wave << 10;

#define SA(nb, h, kt)                                                          \
  do {                                                                         \
    gload_lds16(pA + (h) * KH + (kt),      As + (nb) * 32768 + (h) * 16384 + wb);       \
    gload_lds16(pA + (h) * KH + KU + (kt), As + (nb) * 32768 + (h) * 16384 + 8192 + wb);\
  } while (0)
#define SB(nb, h, kt)                                                          \
  do {                                                                         \
    gload_lds16(pB + (h) * KH + (kt),      Bs + (nb) * 32768 + (h) * 16384 + wb);       \
    gload_lds16(pB + (h) * KH + KU + (kt), Bs + (nb) * 32768 + (h) * 16384 + 8192 + wb);\
  } while (0)

  // fragment reads (32x32 layout)
  const int l5 = lane & 31, h = lane >> 5, l7 = lane & 7;
  const int aoff = ((wr << 6) + l5) << 7;          // (wr*64 + l5) * 128
  const int boff = ((wc << 5) + l5) << 7;          // (wc*32 + l5) * 128
  int ke[4];
#pragma unroll
  for (int s = 0; s < 4; ++s) ke[s] = ((s * 2 + h) ^ l7) << 4;

  i32x16 acc[4][2] = {};   // [mh*2 + mb][nh]
  i32x4 ar[2][4];          // current (mh): [mb][s]
  i32x4 bq[2][4];          // both nh:     [nh][s]

#define LDA(buf, mh)                                                           \
  do {                                                                         \
    const u8* b_ = As + (buf) * 32768 + (mh) * 16384 + aoff;                   \
    _Pragma("unroll") for (int mb = 0; mb < 2; ++mb)                           \
      _Pragma("unroll") for (int s = 0; s < 4; ++s)                            \
        ar[mb][s] = *(const i32x4*)(b_ + mb * 4096 + ke[s]);                   \
  } while (0)
#define LDB(buf, nh)                                                           \
  do {                                                                         \
    const u8* b_ = Bs + (buf) * 32768 + (nh) * 16384 + boff;                   \
    _Pragma("unroll") for (int s = 0; s < 4; ++s)                              \
      bq[nh][s] = *(const i32x4*)(b_ + ke[s]);                                 \
  } while (0)
#define MFMA8(mh, nh)                                                          \
  do {                                                                         \
    __builtin_amdgcn_s_setprio(1);                                             \
    _Pragma("unroll") for (int mb = 0; mb < 2; ++mb)                           \
      _Pragma("unroll") for (int s = 0; s < 4; ++s)                            \
        acc[(mh) * 2 + mb][nh] = __builtin_amdgcn_mfma_i32_32x32x32_i8(        \
            ar[mb][s], bq[nh][s], acc[(mh) * 2 + mb][nh], 0, 0, 0);            \
    __builtin_amdgcn_s_setprio(0);                                             \
  } while (0)

  // prologue: stage tile 0 in consumption order A0,B0,B1,A1
  SA(0, 0, 0);
  SB(0, 0, 0);
  SB(0, 1, 0);
  SA(0, 1, 0);
  asm volatile("s_waitcnt vmcnt(4)" ::: "memory");
  __builtin_amdgcn_s_barrier();

  for (int t = 0; t < NT; ++t) {
    const int buf = t & 1, nb = buf ^ 1;
    const int kt1 = (t + 1) << 7;
    const bool st = (t + 1) < NT;

    // ---- ph1: quadrant (0,0); reads A0(8)+B0(4); stages A0(t+1) ----
    LDA(buf, 0);
    LDB(buf, 0);
    if (st) SA(nb, 0, kt1);
    asm volatile("s_waitcnt lgkmcnt(8)" ::: "memory");
    __builtin_amdgcn_s_barrier();
    asm volatile("s_waitcnt lgkmcnt(0)" ::: "memory");
    MFMA8(0, 0);
    if (st) { asm volatile("s_waitcnt vmcnt(4)" ::: "memory"); }
    else    { asm volatile("s_waitcnt vmcnt(2)" ::: "memory"); }
    __builtin_amdgcn_s_barrier();

    // ---- ph2: quadrant (0,1); reads B1(4); stages B0(t+1) ----
    LDB(buf, 1);
    if (st) SB(nb, 0, kt1);
    __builtin_amdgcn_s_barrier();
    asm volatile("s_waitcnt lgkmcnt(0)" ::: "memory");
    MFMA8(0, 1);
    if (st) { asm volatile("s_waitcnt vmcnt(4)" ::: "memory"); }
    else    { asm volatile("s_waitcnt vmcnt(0)" ::: "memory"); }
    __builtin_amdgcn_s_barrier();

    // ---- ph3: quadrant (1,1); reads A1(8); stages B1(t+1) ----
    LDA(buf, 1);
    if (st) SB(nb, 1, kt1);
    __builtin_amdgcn_s_barrier();
    asm volatile("s_waitcnt lgkmcnt(0)" ::: "memory");
    MFMA8(1, 1);
    __builtin_amdgcn_s_barrier();

    // ---- ph4: quadrant (1,0); no reads; stages A1(t+1) ----
    if (st) SA(nb, 1, kt1);
    __builtin_amdgcn_s_barrier();
    MFMA8(1, 0);
    if (st) { asm volatile("s_waitcnt vmcnt(4)" ::: "memory"); }
    __builtin_amdgcn_s_barrier();
  }

  // epilogue: 32x32 C/D (m74/m101): col = lane&31, row = (r&3)+8*(r>>2)+4*h
#pragma unroll
  for (int mi = 0; mi < 4; ++mi) {
    const int mh = mi >> 1, mb = mi & 1;
    const int rowbase = m0 + mh * 128 + wr * 64 + mb * 32 + h * 4;
#pragma unroll
    for (int nh = 0; nh < 2; ++nh) {
      const int col = n0 + nh * 128 + wc * 32 + l5;
      const float swv = sw[col];
#pragma unroll
      for (int r = 0; r < 16; ++r) {
        const int row = rowbase + (r & 3) + ((r >> 2) << 3);
        C[(size_t)row * N + col] = (float)acc[mi][nh][r] * sx[row] * swv;
      }
    }
  }
#undef SA
#undef SB
#undef LDA
#undef LDB
#undef MFMA8
}

// ---------------- fallback (generic shapes / no workspace): fp32 tiled ----------------
__global__ __launch_bounds__(256) void k_fallback(const float* __restrict__ X,
                                                  const float* __restrict__ W,
                                                  const float* __restrict__ Am,
                                                  const float* __restrict__ Bm,
                                                  float* __restrict__ C,
                                                  int M, int N, int K) {
  __shared__ float Xs[64][16];
  __shared__ float Ws[64][17];
  const int tid = threadIdx.x;
  const int tn = tid & 15, tm = tid >> 4;
  const int m0 = blockIdx.y * 64, n0 = blockIdx.x * 64;
  float acc[4][4] = {};
  for (int kt = 0; kt < K; kt += 16) {
    __syncthreads();
#pragma unroll
    for (int qq = 0; qq < 4; ++qq) {
      int idx = qq * 256 + tid;
      int r = idx >> 4, c = idx & 15;
      Xs[r][c] = X[(size_t)(m0 + r) * K + kt + c];
      float w = W[(size_t)(n0 + r) * K + kt + c];
      float4 b = *(const float4*)(Bm + ((n0 + r) << 2));
      w += 4.f * (b.x * Am[kt + c] + b.y * Am[4096 + kt + c] +
                  b.z * Am[8192 + kt + c] + b.w * Am[12288 + kt + c]);
      Ws[r][c] = w;
    }
    __syncthreads();
#pragma unroll
    for (int k = 0; k < 16; ++k) {
      float xv[4], wv[4];
#pragma unroll
      for (int i = 0; i < 4; ++i) xv[i] = Xs[tm * 4 + i][k];
#pragma unroll
      for (int j = 0; j < 4; ++j) wv[j] = Ws[tn * 4 + j][k];
#pragma unroll
      for (int i = 0; i < 4; ++i)
#pragma unroll
        for (int j = 0; j < 4; ++j) acc[i][j] += xv[i] * wv[j];
    }
  }
#pragma unroll
  for (int i = 0; i < 4; ++i)
#pragma unroll
    for (int j = 0; j < 4; ++j)
      C[(size_t)(m0 + tm * 4 + i) * N + n0 + tn * 4 + j] = acc[i][j];
}

extern "C" void kernel_launch(void* const* d_in, const int* in_sizes, int n_in,
                              void* d_out, int out_size, void* d_ws, size_t ws_size,
                              hipStream_t stream) {
  const float* x  = (const float*)d_in[0];
  const float* W  = (const float*)d_in[1];
  const float* lA = (const float*)d_in[2];
  const float* lB = (const float*)d_in[3];
  float* out = (float*)d_out;
  const int K = 4096, N = 4096;
  const int M = in_sizes[0] / K;   // 8192
  const size_t need = (size_t)(M + N) * K + (size_t)(M + N) * sizeof(float);

  if (ws_size >= need && (M % 256) == 0) {
    i8* xb = (i8*)d_ws;
    i8* wb = xb + (size_t)M * K;
    float* sx = (float*)(wb + (size_t)N * K);
    float* sw = sx + M;
    k_quant<<<dim3(M + N), dim3(256), 0, stream>>>(x, W, lA, lB, xb, wb, sx, sw, M);
    k_gq8<<<dim3(N / 256, M / 256), dim3(512), 0, stream>>>(
        (const u8*)xb, (const u8*)wb, sx, sw, out, M, N, K);
  } else {
    k_fallback<<<dim3(N / 64, M / 64), dim3(256), 0, stream>>>(x, W, lA, lB, out, M, N, K);
  }
}

// Round 17
// 191.545 us; speedup vs baseline: 1.0998x; 1.0998x over previous
//
#include <hip/hip_runtime.h>
#include <stdint.h>

typedef signed char i8;
typedef unsigned char u8;
typedef __attribute__((ext_vector_type(4))) int i32x4;

__device__ __forceinline__ void gload_lds16(const void* g, void* l) {
  __builtin_amdgcn_global_load_lds(
      (__attribute__((address_space(1))) void*)const_cast<void*>(g),
      (__attribute__((address_space(3))) void*)l, 16, 0, 0);
}

// ---------- fused prep: one grid quantizes both x (rows) and W' (rows) ----------
// bid < M: row of x.  bid >= M: row o = bid - M of W' = W + 4*B@A.
// Per-row absmax -> i8 + f32 scale.  256 threads/row.
__global__ __launch_bounds__(256) void k_quant(const float* __restrict__ x,
                                               const float* __restrict__ W,
                                               const float* __restrict__ Am,
                                               const float* __restrict__ Bm,
                                               i8* __restrict__ xq,
                                               i8* __restrict__ wq,
                                               float* __restrict__ sx,
                                               float* __restrict__ sw, int M) {
  const int bid = blockIdx.x, t = threadIdx.x;
  const bool isx = bid < M;
  const int row = isx ? bid : bid - M;
  float4 v[4];
  float m = 0.f;
  if (isx) {
    const float4* src = (const float4*)(x + (size_t)row * 4096);
#pragma unroll
    for (int j = 0; j < 4; ++j) {
      v[j] = src[j * 256 + t];
      m = fmaxf(m, fmaxf(fmaxf(fabsf(v[j].x), fabsf(v[j].y)),
                         fmaxf(fabsf(v[j].z), fabsf(v[j].w))));
    }
  } else {
    const float4 b4 = *(const float4*)(Bm + (row << 2));
#pragma unroll
    for (int j = 0; j < 4; ++j) {
      const int i = (j * 256 + t) * 4;
      float4 w  = *(const float4*)(W + ((size_t)row << 12) + i);
      float4 a0 = *(const float4*)(Am + i);
      float4 a1 = *(const float4*)(Am + 4096 + i);
      float4 a2 = *(const float4*)(Am + 8192 + i);
      float4 a3 = *(const float4*)(Am + 12288 + i);
      w.x += 4.f * (b4.x * a0.x + b4.y * a1.x + b4.z * a2.x + b4.w * a3.x);
      w.y += 4.f * (b4.x * a0.y + b4.y * a1.y + b4.z * a2.y + b4.w * a3.y);
      w.z += 4.f * (b4.x * a0.z + b4.y * a1.z + b4.z * a2.z + b4.w * a3.z);
      w.w += 4.f * (b4.x * a0.w + b4.y * a1.w + b4.z * a2.w + b4.w * a3.w);
      v[j] = w;
      m = fmaxf(m, fmaxf(fmaxf(fabsf(w.x), fabsf(w.y)), fmaxf(fabsf(w.z), fabsf(w.w))));
    }
  }
#pragma unroll
  for (int off = 32; off; off >>= 1) m = fmaxf(m, __shfl_xor(m, off));
  __shared__ float wmax[4];
  if ((t & 63) == 0) wmax[t >> 6] = m;
  __syncthreads();
  m = fmaxf(fmaxf(wmax[0], wmax[1]), fmaxf(wmax[2], wmax[3]));
  const float inv = m > 0.f ? 127.f / m : 0.f;
  if (t == 0) { if (isx) sx[row] = m / 127.f; else sw[row] = m / 127.f; }
  i8* out = isx ? xq : wq;
#pragma unroll
  for (int j = 0; j < 4; ++j) {
    int q0 = (int)rintf(fmaxf(fminf(v[j].x * inv, 127.f), -127.f));
    int q1 = (int)rintf(fmaxf(fminf(v[j].y * inv, 127.f), -127.f));
    int q2 = (int)rintf(fmaxf(fminf(v[j].z * inv, 127.f), -127.f));
    int q3 = (int)rintf(fmaxf(fminf(v[j].w * inv, 127.f), -127.f));
    uint32_t p = (q0 & 255) | ((q1 & 255) << 8) | ((q2 & 255) << 16) | ((q3 & 255) << 24);
    *(uint32_t*)(out + (size_t)row * 4096 + (j * 256 + t) * 4) = p;
  }
}

// ===== i8 GEMM — R9/R15 structure verbatim (measured best: 143 us GEMM) =====
// C[m][n] = sx[m]*sw[n] * sum_k Aq[m][k]*Bq[n][k].  256x256 tile, 8 waves
// (interleaved mapping), quadrant phases, double-buffered LDS (128 KiB),
// counted vmcnt(4) chain (never 0 in loop), XOR swizzle (0 conflicts, measured).
// NOTE (R16 lesson): 16x16 fragment reads give 2 lanes/bank-column (free);
// 32x32 reads are geometrically >=4-way-conflicted with 128-B rows — do not
// switch MFMA shape on this skeleton.
__global__ __launch_bounds__(512, 2) void k_gq8(const u8* __restrict__ Ag,
                                                const u8* __restrict__ Bg,
                                                const float* __restrict__ sx,
                                                const float* __restrict__ sw,
                                                float* __restrict__ C,
                                                int M, int N, int K) {
  __shared__ __attribute__((aligned(16))) u8 As[2 * 32768];
  __shared__ __attribute__((aligned(16))) u8 Bs[2 * 32768];
  const int tid  = threadIdx.x;
  const int wave = tid >> 6, lane = tid & 63;
  const int wr = wave >> 2, wc = wave & 3;
  const int m0 = blockIdx.y * 256, n0 = blockIdx.x * 256;
  const int NT = K >> 7;                           // 128-byte K-tiles

  // staging: unit = 64 rows x 128 B = 8 KB = 512 lanes x 16B (1 gload)
  const int srow = tid >> 3;                       // 0..63
  const int csrc = (tid & 7) ^ (srow & 7);         // pre-swizzled source chunk
  const u8* pA = Ag + (size_t)(m0 + srow) * K + csrc * 16;
  const u8* pB = Bg + (size_t)(n0 + srow) * K + csrc * 16;
  const size_t KH = (size_t)128 * K;               // half stride
  const size_t KU = (size_t)64 * K;                // unit stride
  const int wb = wave << 10;                       // wave-uniform LDS base (bytes)

#define SA(nb, h, kt)                                                          \
  do {                                                                         \
    gload_lds16(pA + (h) * KH + (kt),      As + (nb) * 32768 + (h) * 16384 + wb);       \
    gload_lds16(pA + (h) * KH + KU + (kt), As + (nb) * 32768 + (h) * 16384 + 8192 + wb);\
  } while (0)
#define SB(nb, h, kt)                                                          \
  do {                                                                         \
    gload_lds16(pB + (h) * KH + (kt),      Bs + (nb) * 32768 + (h) * 16384 + wb);       \
    gload_lds16(pB + (h) * KH + KU + (kt), Bs + (nb) * 32768 + (h) * 16384 + 8192 + wb);\
  } while (0)

  // fragment reads: row 128 B; phys chunk = (ks*4 + q) ^ (lane&7)
  const int l4 = lane & 15, q = lane >> 4, l7 = lane & 7;
  const int ke0 = (q ^ l7) << 4;                   // bytes; ks=1 -> ke0 ^ 64
  const int aoff = ((wr << 6) + l4) << 7;          // (wr*64 + l4)*128
  const int boff = ((wc << 5) + l4) << 7;          // (wc*32 + l4)*128

  i32x4 acc[8][4] = {};
  i32x4 ar[4][2];      // current A-half [f][ks]
  i32x4 bq[2][2][2];   // both B-halves [nh][g][ks]

#define LDA(buf, mh)                                                           \
  do {                                                                         \
    const u8* b_ = As + (buf) * 32768 + (mh) * 16384 + aoff;                   \
    _Pragma("unroll") for (int f = 0; f < 4; ++f) {                            \
      ar[f][0] = *(const i32x4*)(b_ + f * 2048 + ke0);                         \
      ar[f][1] = *(const i32x4*)(b_ + f * 2048 + (ke0 ^ 64));                  \
    }                                                                          \
  } while (0)
#define LDB(buf, nh)                                                           \
  do {                                                                         \
    const u8* b_ = Bs + (buf) * 32768 + (nh) * 16384 + boff;                   \
    _Pragma("unroll") for (int g = 0; g < 2; ++g) {                            \
      bq[nh][g][0] = *(const i32x4*)(b_ + g * 2048 + ke0);                     \
      bq[nh][g][1] = *(const i32x4*)(b_ + g * 2048 + (ke0 ^ 64));              \
    }                                                                          \
  } while (0)
#define MFMA16(mh, nh)                                                         \
  do {                                                                         \
    __builtin_amdgcn_s_setprio(1);                                             \
    _Pragma("unroll") for (int f = 0; f < 4; ++f)                              \
      _Pragma("unroll") for (int g = 0; g < 2; ++g)                            \
        _Pragma("unroll") for (int ks = 0; ks < 2; ++ks)                       \
          acc[(mh) * 4 + f][(nh) * 2 + g] =                                    \
              __builtin_amdgcn_mfma_i32_16x16x64_i8(                           \
                  ar[f][ks], bq[nh][g][ks], acc[(mh) * 4 + f][(nh) * 2 + g],   \
                  0, 0, 0);                                                    \
    __builtin_amdgcn_s_setprio(0);                                             \
  } while (0)

  // prologue: stage tile 0 in consumption order A0,B0,B1,A1
  SA(0, 0, 0);
  SB(0, 0, 0);
  SB(0, 1, 0);
  SA(0, 1, 0);
  asm volatile("s_waitcnt vmcnt(4)" ::: "memory");   // A0,B0 landed
  __builtin_amdgcn_s_barrier();

  for (int t = 0; t < NT; ++t) {
    const int buf = t & 1, nb = buf ^ 1;
    const int kt1 = (t + 1) << 7;
    const bool st = (t + 1) < NT;

    // ---- ph1: quadrant (0,0); reads A0(8)+B0(4); stages A0(t+1) ----
    LDA(buf, 0);
    LDB(buf, 0);
    if (st) SA(nb, 0, kt1);
    asm volatile("s_waitcnt lgkmcnt(8)" ::: "memory");
    __builtin_amdgcn_s_barrier();
    asm volatile("s_waitcnt lgkmcnt(0)" ::: "memory");
    MFMA16(0, 0);
    if (st) { asm volatile("s_waitcnt vmcnt(4)" ::: "memory"); }
    else    { asm volatile("s_waitcnt vmcnt(2)" ::: "memory"); }
    __builtin_amdgcn_s_barrier();

    // ---- ph2: quadrant (0,1); reads B1(4); stages B0(t+1) ----
    LDB(buf, 1);
    if (st) SB(nb, 0, kt1);
    __builtin_amdgcn_s_barrier();
    asm volatile("s_waitcnt lgkmcnt(0)" ::: "memory");
    MFMA16(0, 1);
    if (st) { asm volatile("s_waitcnt vmcnt(4)" ::: "memory"); }
    else    { asm volatile("s_waitcnt vmcnt(0)" ::: "memory"); }
    __builtin_amdgcn_s_barrier();

    // ---- ph3: quadrant (1,1); reads A1(8); stages B1(t+1) ----
    LDA(buf, 1);
    if (st) SB(nb, 1, kt1);
    __builtin_amdgcn_s_barrier();
    asm volatile("s_waitcnt lgkmcnt(0)" ::: "memory");
    MFMA16(1, 1);
    __builtin_amdgcn_s_barrier();

    // ---- ph4: quadrant (1,0); no reads; stages A1(t+1) ----
    if (st) SA(nb, 1, kt1);
    __builtin_amdgcn_s_barrier();
    MFMA16(1, 0);
    if (st) { asm volatile("s_waitcnt vmcnt(4)" ::: "memory"); }
    __builtin_amdgcn_s_barrier();
  }

  // epilogue: C/D col = lane&15, row = (lane>>4)*4 + reg (dtype-independent)
  float swv[4];
#pragma unroll
  for (int j = 0; j < 4; ++j)
    swv[j] = sw[n0 + (j >> 1) * 128 + wc * 32 + (j & 1) * 16 + l4];
#pragma unroll
  for (int i = 0; i < 8; ++i) {
    const int mh = i >> 2, f = i & 3;
    const int row = m0 + mh * 128 + wr * 64 + f * 16 + q * 4;
#pragma unroll
    for (int j = 0; j < 4; ++j) {
      const int nh = j >> 1, g = j & 1;
      const int col = n0 + nh * 128 + wc * 32 + g * 16 + l4;
#pragma unroll
      for (int v = 0; v < 4; ++v)
        C[(size_t)(row + v) * N + col] = (float)acc[i][j][v] * sx[row + v] * swv[j];
    }
  }
#undef SA
#undef SB
#undef LDA
#undef LDB
#undef MFMA16
}

// ---------------- fallback (generic shapes / no workspace): fp32 tiled ----------------
__global__ __launch_bounds__(256) void k_fallback(const float* __restrict__ X,
                                                  const float* __restrict__ W,
                                                  const float* __restrict__ Am,
                                                  const float* __restrict__ Bm,
                                                  float* __restrict__ C,
                                                  int M, int N, int K) {
  __shared__ float Xs[64][16];
  __shared__ float Ws[64][17];
  const int tid = threadIdx.x;
  const int tn = tid & 15, tm = tid >> 4;
  const int m0 = blockIdx.y * 64, n0 = blockIdx.x * 64;
  float acc[4][4] = {};
  for (int kt = 0; kt < K; kt += 16) {
    __syncthreads();
#pragma unroll
    for (int qq = 0; qq < 4; ++qq) {
      int idx = qq * 256 + tid;
      int r = idx >> 4, c = idx & 15;
      Xs[r][c] = X[(size_t)(m0 + r) * K + kt + c];
      float w = W[(size_t)(n0 + r) * K + kt + c];
      float4 b = *(const float4*)(Bm + ((n0 + r) << 2));
      w += 4.f * (b.x * Am[kt + c] + b.y * Am[4096 + kt + c] +
                  b.z * Am[8192 + kt + c] + b.w * Am[12288 + kt + c]);
      Ws[r][c] = w;
    }
    __syncthreads();
#pragma unroll
    for (int k = 0; k < 16; ++k) {
      float xv[4], wv[4];
#pragma unroll
      for (int i = 0; i < 4; ++i) xv[i] = Xs[tm * 4 + i][k];
#pragma unroll
      for (int j = 0; j < 4; ++j) wv[j] = Ws[tn * 4 + j][k];
#pragma unroll
      for (int i = 0; i < 4; ++i)
#pragma unroll
        for (int j = 0; j < 4; ++j) acc[i][j] += xv[i] * wv[j];
    }
  }
#pragma unroll
  for (int i = 0; i < 4; ++i)
#pragma unroll
    for (int j = 0; j < 4; ++j)
      C[(size_t)(m0 + tm * 4 + i) * N + n0 + tn * 4 + j] = acc[i][j];
}

extern "C" void kernel_launch(void* const* d_in, const int* in_sizes, int n_in,
                              void* d_out, int out_size, void* d_ws, size_t ws_size,
                              hipStream_t stream) {
  const float* x  = (const float*)d_in[0];
  const float* W  = (const float*)d_in[1];
  const float* lA = (const float*)d_in[2];
  const float* lB = (const float*)d_in[3];
  float* out = (float*)d_out;
  const int K = 4096, N = 4096;
  const int M = in_sizes[0] / K;   // 8192
  const size_t need = (size_t)(M + N) * K + (size_t)(M + N) * sizeof(float);

  if (ws_size >= need && (M % 256) == 0) {
    i8* xb = (i8*)d_ws;
    i8* wb = xb + (size_t)M * K;
    float* sx = (float*)(wb + (size_t)N * K);
    float* sw = sx + M;
    k_quant<<<dim3(M + N), dim3(256), 0, stream>>>(x, W, lA, lB, xb, wb, sx, sw, M);
    k_gq8<<<dim3(N / 256, M / 256), dim3(512), 0, stream>>>(
        (const u8*)xb, (const u8*)wb, sx, sw, out, M, N, K);
  } else {
    k_fallback<<<dim3(N / 64, M / 64), dim3(256), 0, stream>>>(x, W, lA, lB, out, M, N, K);
  }
}